// Round 8
// baseline (271.167 us; speedup 1.0000x reference)
//
#include <hip/hip_runtime.h>
#include <hip/hip_cooperative_groups.h>

namespace cg = cooperative_groups;

// B=4, C=256, H=W=64 (N=4096). QKV 1x1conv -> spatial attention (softmax over
// j only => independent per-64-key-chunk softmax) -> channel LayerNorm.
// f16 MFMA 32x32x16, fp32 accumulation.
//
// R8: single cooperative kernel. Phase 1: each block computes Q/K/V for its
// own (b, 64-position) tile (x transpose-staged, weight halves in LDS,
// 8 waves). grid.sync(). Phase 2: attn with 2 barriers/chunk (K-commit moved
// into the softmax interval; PV_i + S_{i+1} share one interval). LDS regions
// phase-aliased in one 156.7 KB block (1 block/CU).

#define CDIM 256
#define NPOS 4096
#define BATCH 4
#define EPSV 1e-5f

typedef _Float16 f16;
typedef __attribute__((ext_vector_type(8))) _Float16 f16x8;
typedef __attribute__((ext_vector_type(4))) float f32x4;
typedef __attribute__((ext_vector_type(16))) float f32x16;

#define WST       264   // f16; 528B = 33*16 -> b128-aligned rows
#define S_STRIDE  68    // f32; 272B = 17*16
#define P_STRIDE  72
#define DS2       136   // f16; 272B = 17*16 (QK output half staging)
#define DSV       72    // f16; 144B = 9*16  (V output half staging)
#define FT_STRIDE 66

// MFMA 32x32x16 f16:
//   A: lane l holds A[m=l&31][k=(l>>5)*8+j]
//   B: lane l holds B[k=(l>>5)*8+j][n=l&31]
//   C/D: lane l, reg r -> col=l&31, row=(r&3)+8*(r>>2)+4*(l>>5)

static __device__ __forceinline__ f16x8 cvt8(const float* __restrict__ p) {
    float4 w0 = *(const float4*)p;
    float4 w1 = *(const float4*)(p + 4);
    f16x8 r;
    r[0] = (f16)w0.x; r[1] = (f16)w0.y; r[2] = (f16)w0.z; r[3] = (f16)w0.w;
    r[4] = (f16)w1.x; r[5] = (f16)w1.y; r[6] = (f16)w1.z; r[7] = (f16)w1.w;
    return r;
}

__global__ __launch_bounds__(512, 1) void fused_kernel(
    const float* __restrict__ x1, const float* __restrict__ x2,
    const float* __restrict__ qw, const float* __restrict__ kw,
    const float* __restrict__ vw,
    const float* __restrict__ qb, const float* __restrict__ kb,
    const float* __restrict__ vb,
    const float* __restrict__ ln_w, const float* __restrict__ ln_b,
    f16* __restrict__ Qg, f16* __restrict__ Kg, f16* __restrict__ Vg,
    float* __restrict__ out)
{
    // LDS layout (byte offsets), phase-aliased:
    //  qkv : Xs1 0..33792 | Xs2 33792..67584 | Wh 67584..135168
    //        Ds 135168..153600 | biasS 153600..156672
    //  attn: Ks[2] 0..67584 | Ss[2] 67584..102400 | Ps[2] 102400..120832
    //        lnw 120832 lnb 121856 redS 122880 redQ 123904 mu 124928 rs 125184
    __shared__ __align__(16) char SM[156672];

    const int t  = threadIdx.x;
    const int b  = blockIdx.x >> 6;
    const int p0 = (blockIdx.x & 63) << 6;
    const int l  = t & 63, lm = l & 31, lh = l >> 5;

    // ======================= Phase 1: QKV =======================
    {
        f16* Xs1 = (f16*)SM;
        f16* Xs2 = Xs1 + 64 * WST;
        f16* Wh  = Xs2 + 64 * WST;
        f16* Ds  = (f16*)(SM + 135168);
        float* biasS = (float*)(SM + 153600);   // [768]

        const int w8 = t >> 6;          // 0..7
        const int pt = w8 & 1;          // p-tile
        const int oq = w8 >> 1;         // o-tile within 128-half (0..3)

        if (t < 256) { biasS[t] = qb[t]; biasS[256 + t] = kb[t]; biasS[512 + t] = vb[t]; }

        // transpose-stage x1 -> Xs1, x2 -> Xs2 ([c][p] fp32 -> [p][c] f16)
        {
            const int p   = t & 63;
            const int cg2 = (t >> 6) * 2;
            const float* s1 = x1 + (size_t)b * CDIM * NPOS + p0 + p;
            const float* s2 = x2 + (size_t)b * CDIM * NPOS + p0 + p;
            #pragma unroll
            for (int c = cg2; c < CDIM; c += 16) {
                Xs1[p * WST + c]     = (f16)s1[(size_t)c * NPOS];
                Xs1[p * WST + c + 1] = (f16)s1[(size_t)(c + 1) * NPOS];
                Xs2[p * WST + c]     = (f16)s2[(size_t)c * NPOS];
                Xs2[p * WST + c + 1] = (f16)s2[(size_t)(c + 1) * NPOS];
            }
        }

        for (int pr = 0; pr < 3; ++pr) {
            const float* Wp = pr == 0 ? qw : pr == 1 ? kw : vw;
            const f16* X = (pr == 0) ? Xs1 : Xs2;
            for (int h = 0; h < 2; ++h) {
                __syncthreads();   // prev reads of Wh/Ds done; first iter: Xs/bias ready
                // stage weight half: 128 o-rows x 256 c, fp32 -> f16
                #pragma unroll
                for (int i = 0; i < 8; ++i) {
                    int gi = t + i * 512;
                    int row = gi >> 5, col = (gi & 31) * 8;
                    *(f16x8*)&Wh[row * WST + col] =
                        cvt8(Wp + (size_t)(h * 128 + row) * CDIM + col);
                }
                __syncthreads();   // Wh ready

                f32x16 accA = {}, accB = {};
                #pragma unroll
                for (int ks = 0; ks < 16; ks += 2) {
                    f16x8 xa = *(const f16x8*)&X[(pt * 32 + lm) * WST + ks * 16 + lh * 8];
                    f16x8 wa = *(const f16x8*)&Wh[(oq * 32 + lm) * WST + ks * 16 + lh * 8];
                    f16x8 xb = *(const f16x8*)&X[(pt * 32 + lm) * WST + (ks + 1) * 16 + lh * 8];
                    f16x8 wb = *(const f16x8*)&Wh[(oq * 32 + lm) * WST + (ks + 1) * 16 + lh * 8];
                    if (pr < 2) {
                        accA = __builtin_amdgcn_mfma_f32_32x32x16_f16(xa, wa, accA, 0, 0, 0);
                        accB = __builtin_amdgcn_mfma_f32_32x32x16_f16(xb, wb, accB, 0, 0, 0);
                    } else {
                        accA = __builtin_amdgcn_mfma_f32_32x32x16_f16(wa, xa, accA, 0, 0, 0);
                        accB = __builtin_amdgcn_mfma_f32_32x32x16_f16(wb, xb, accB, 0, 0, 0);
                    }
                }

                if (pr < 2) {
                    // D[p][o_l]: col(lane) = o_l, row(reg) = p_l
                    int o_l = oq * 32 + lm;
                    float bv = biasS[pr * 256 + h * 128 + o_l];
                    #pragma unroll
                    for (int r = 0; r < 16; ++r) {
                        int p_l = pt * 32 + (r & 3) + 8 * (r >> 2) + 4 * lh;
                        Ds[p_l * DS2 + o_l] = (f16)(accA[r] + accB[r] + bv);
                    }
                } else {
                    // D[o_l][p]: col(lane) = p, row(reg) = o_l
                    #pragma unroll
                    for (int r = 0; r < 16; ++r) {
                        int o_l = oq * 32 + (r & 3) + 8 * (r >> 2) + 4 * lh;
                        Ds[o_l * DSV + pt * 32 + lm] =
                            (f16)(accA[r] + accB[r] + biasS[512 + h * 128 + o_l]);
                    }
                }
                __syncthreads();   // Ds ready

                if (pr < 2) {
                    f16* Out = (pr == 0) ? Qg : Kg;
                    #pragma unroll
                    for (int j = 0; j < 2; ++j) {
                        int idx = t + j * 512;           // 0..1023
                        int row = idx >> 4;              // 0..63 (p)
                        int cc  = (idx & 15) * 8;        // 0..120 (o within half)
                        *(f16x8*)(Out + ((size_t)(b * NPOS + p0 + row)) * CDIM + h * 128 + cc) =
                            *(const f16x8*)&Ds[row * DS2 + cc];
                    }
                } else {
                    #pragma unroll
                    for (int j = 0; j < 2; ++j) {
                        int idx = t + j * 512;
                        int row = idx >> 3;              // 0..127 (o within half)
                        int cc  = (idx & 7) * 8;         // 0..56 (p)
                        *(f16x8*)(Vg + ((size_t)(b * CDIM + h * 128 + row)) * NPOS + p0 + cc) =
                            *(const f16x8*)&Ds[row * DSV + cc];
                    }
                }
            }
        }
    }

    cg::this_grid().sync();

    // ======================= Phase 2: attention + LN =======================
    {
        f16*   Ks    = (f16*)SM;                    // [2][64*WST]
        float* Ss    = (float*)(SM + 67584);        // [2][64*S_STRIDE]
        f16*   Ps    = (f16*)(SM + 102400);         // [2][64*P_STRIDE]
        float* lnw_s = (float*)(SM + 120832);
        float* lnb_s = (float*)(SM + 121856);
        float* redS  = (float*)(SM + 122880);
        float* redQ  = (float*)(SM + 123904);
        float* mu_s  = (float*)(SM + 124928);
        float* rs_s  = (float*)(SM + 125184);
        float* Ftmp  = (float*)SM;                  // aliases Ks, 256*66*4 B

        const int g  = t >> 8;           // wave-group 0/1
        const int tl = t & 255;
        const int wl = (t >> 6) & 3;

        if (t < 256) { lnw_s[t] = ln_w[t]; lnb_s[t] = ln_b[t]; }

        const int spt = wl & 1;          // wave's S tile: p-tile spt, key-tile skt
        const int skt = wl >> 1;

        f16*   KsG = Ks + g * 64 * WST;
        float* SsG = Ss + g * 64 * S_STRIDE;
        f16*   PsG = Ps + g * 64 * P_STRIDE;

        // Q fragments (L2-hot: written by this very block in phase 1)
        f16x8 qf[16];
        {
            const f16* qptr = Qg + (size_t)(b * NPOS + p0 + spt * 32 + lm) * CDIM + lh * 8;
            #pragma unroll
            for (int ks = 0; ks < 16; ++ks) qf[ks] = *(const f16x8*)(qptr + ks * 16);
        }

        const int kr = tl >> 5, koff = (tl & 31) * 8;
        f16x8 kreg[8];
        auto issue_k = [&](int ch) {
            const int i0 = ch * 64;
            #pragma unroll
            for (int r = 0; r < 8; ++r)
                kreg[r] = *(const f16x8*)(Kg + (size_t)(b * NPOS + i0 + r * 8 + kr) * CDIM + koff);
        };

        const f16* vbase0 = Vg + (size_t)(b * CDIM + wl * 64 + lm) * NPOS;
        const f16* vbase1 = Vg + (size_t)(b * CDIM + wl * 64 + 32 + lm) * NPOS;

        // prologue: commit chunk g, prefetch chunk g+2
        issue_k(g);
        #pragma unroll
        for (int r = 0; r < 8; ++r)
            *(f16x8*)&KsG[(r * 8 + kr) * WST + koff] = kreg[r];
        issue_k(g + 2);

        f32x16 facc[4] = {};   // [i=c-tile(2)][j=p-tile(2)]
        __syncthreads();       // Ks(chunk g) ready

        for (int it = 0; it < 32; ++it) {
            const int i0 = (2 * it + g) * 64;

            // V fragments for this chunk (consumed after 2 barriers)
            f16x8 vf0[4], vf1[4];
            #pragma unroll
            for (int ks = 0; ks < 4; ++ks) {
                vf0[ks] = *(const f16x8*)(vbase0 + i0 + ks * 16 + lh * 8);
                vf1[ks] = *(const f16x8*)(vbase1 + i0 + ks * 16 + lh * 8);
            }

            // S = Q K^T
            f32x16 sacc = {};
            #pragma unroll
            for (int ks = 0; ks < 16; ++ks) {
                f16x8 bb = *(const f16x8*)&KsG[(skt * 32 + lm) * WST + ks * 16 + lh * 8];
                sacc = __builtin_amdgcn_mfma_f32_32x32x16_f16(qf[ks], bb, sacc, 0, 0, 0);
            }
            #pragma unroll
            for (int r = 0; r < 16; ++r) {
                int row = (r & 3) + 8 * (r >> 2) + 4 * lh;
                SsG[(spt * 32 + row) * S_STRIDE + skt * 32 + lm] = sacc[r];
            }
            __syncthreads();   // B: Ss ready; all S-reads of Ks done

            // softmax per row (4 threads/row x 16 elems)
            {
                const int r  = tl >> 2;
                const int sg = (tl & 3) * 16;
                const float* srow = &SsG[r * S_STRIDE + sg];
                float v[16];
                f32x4 a0 = *(const f32x4*)(srow);
                f32x4 a1 = *(const f32x4*)(srow + 4);
                f32x4 a2 = *(const f32x4*)(srow + 8);
                f32x4 a3 = *(const f32x4*)(srow + 12);
                v[0]=a0[0]; v[1]=a0[1]; v[2]=a0[2]; v[3]=a0[3];
                v[4]=a1[0]; v[5]=a1[1]; v[6]=a1[2]; v[7]=a1[3];
                v[8]=a2[0]; v[9]=a2[1]; v[10]=a2[2]; v[11]=a2[3];
                v[12]=a3[0]; v[13]=a3[1]; v[14]=a3[2]; v[15]=a3[3];
                float m = v[0];
                #pragma unroll
                for (int i = 1; i < 16; ++i) m = fmaxf(m, v[i]);
                m = fmaxf(m, __shfl_xor(m, 1));
                m = fmaxf(m, __shfl_xor(m, 2));
                float s = 0.f;
                #pragma unroll
                for (int i = 0; i < 16; ++i) { float e = __expf(v[i] - m); v[i] = e; s += e; }
                s += __shfl_xor(s, 1);
                s += __shfl_xor(s, 2);
                float inv = __builtin_amdgcn_rcpf(s);
                f16x8 h0, h1;
                #pragma unroll
                for (int i = 0; i < 8; ++i) { h0[i] = (f16)(v[i] * inv); h1[i] = (f16)(v[i + 8] * inv); }
                *(f16x8*)&PsG[r * P_STRIDE + sg]     = h0;
                *(f16x8*)&PsG[r * P_STRIDE + sg + 8] = h1;
            }

            // commit next chunk's K (Ks is dead in this interval) + prefetch
            if (it < 31) {
                #pragma unroll
                for (int r = 0; r < 8; ++r)
                    *(f16x8*)&KsG[(r * 8 + kr) * WST + koff] = kreg[r];
                if (it < 30) issue_k(2 * it + g + 4);
            }
            __syncthreads();   // C: Ps ready AND next Ks ready

            // F += V * P^T  (next iteration's S follows in the same interval)
            #pragma unroll
            for (int ks = 0; ks < 4; ++ks) {
                f16x8 bp0 = *(const f16x8*)&PsG[lm * P_STRIDE + ks * 16 + lh * 8];
                f16x8 bp1 = *(const f16x8*)&PsG[(32 + lm) * P_STRIDE + ks * 16 + lh * 8];
                facc[0] = __builtin_amdgcn_mfma_f32_32x32x16_f16(vf0[ks], bp0, facc[0], 0, 0, 0);
                facc[1] = __builtin_amdgcn_mfma_f32_32x32x16_f16(vf0[ks], bp1, facc[1], 0, 0, 0);
                facc[2] = __builtin_amdgcn_mfma_f32_32x32x16_f16(vf1[ks], bp0, facc[2], 0, 0, 0);
                facc[3] = __builtin_amdgcn_mfma_f32_32x32x16_f16(vf1[ks], bp1, facc[3], 0, 0, 0);
            }
        }

        // ---- merge group 1 -> group 0 via Ftmp (aliases Ks) ----
        __syncthreads();   // D: all PV done
        if (g == 1) {
            #pragma unroll
            for (int ii = 0; ii < 2; ++ii)
                #pragma unroll
                for (int jj = 0; jj < 2; ++jj)
                    #pragma unroll
                    for (int r = 0; r < 16; ++r) {
                        int c = wl * 64 + ii * 32 + (r & 3) + 8 * (r >> 2) + 4 * lh;
                        int p = jj * 32 + lm;
                        Ftmp[c * FT_STRIDE + p] = facc[ii * 2 + jj][r];
                    }
        }
        __syncthreads();   // E
        if (g == 0) {
            float ps0 = 0.f, ps1 = 0.f, pq0 = 0.f, pq1 = 0.f;
            #pragma unroll
            for (int ii = 0; ii < 2; ++ii)
                #pragma unroll
                for (int jj = 0; jj < 2; ++jj)
                    #pragma unroll
                    for (int r = 0; r < 16; ++r) {
                        int c = wl * 64 + ii * 32 + (r & 3) + 8 * (r >> 2) + 4 * lh;
                        int p = jj * 32 + lm;
                        facc[ii * 2 + jj][r] += Ftmp[c * FT_STRIDE + p];
                    }
            #pragma unroll
            for (int ii = 0; ii < 2; ++ii) {
                #pragma unroll
                for (int r = 0; r < 16; ++r) {
                    float a = facc[ii * 2 + 0][r];
                    float c = facc[ii * 2 + 1][r];
                    ps0 += a; pq0 += a * a;
                    ps1 += c; pq1 += c * c;
                }
            }
            ps0 += __shfl_xor(ps0, 32); pq0 += __shfl_xor(pq0, 32);
            ps1 += __shfl_xor(ps1, 32); pq1 += __shfl_xor(pq1, 32);
            if (lh == 0) {
                redS[wl * 64 + lm] = ps0;        redQ[wl * 64 + lm] = pq0;
                redS[wl * 64 + 32 + lm] = ps1;   redQ[wl * 64 + 32 + lm] = pq1;
            }
        }
        __syncthreads();   // F
        if (t < 64) {
            float s = redS[t] + redS[64 + t] + redS[128 + t] + redS[192 + t];
            float q = redQ[t] + redQ[64 + t] + redQ[128 + t] + redQ[192 + t];
            float mean = s * (1.0f / 256.0f);
            float var  = q * (1.0f / 256.0f) - mean * mean;
            mu_s[t] = mean;
            rs_s[t] = rsqrtf(var + EPSV);
        }
        __syncthreads();   // G
        if (g == 0) {
            #pragma unroll
            for (int ii = 0; ii < 2; ++ii) {
                #pragma unroll
                for (int jj = 0; jj < 2; ++jj) {
                    int p = jj * 32 + lm;
                    float mu = mu_s[p], rs = rs_s[p];
                    float* dst = out + (size_t)b * CDIM * NPOS + p0 + p;
                    #pragma unroll
                    for (int r = 0; r < 16; ++r) {
                        int c = wl * 64 + ii * 32 + (r & 3) + 8 * (r >> 2) + 4 * lh;
                        float vL = facc[ii * 2 + jj][r];
                        dst[(size_t)c * NPOS] = (vL - mu) * rs * lnw_s[c] + lnb_s[c];
                    }
                }
            }
        }
    }
}

// ---------------------------------------------------------------------------
extern "C" void kernel_launch(void* const* d_in, const int* in_sizes, int n_in,
                              void* d_out, int out_size, void* d_ws, size_t ws_size,
                              hipStream_t stream)
{
    const float* x1  = (const float*)d_in[0];
    const float* x2  = (const float*)d_in[1];
    const float* qw  = (const float*)d_in[2];
    const float* qb  = (const float*)d_in[3];
    const float* kw  = (const float*)d_in[4];
    const float* kb  = (const float*)d_in[5];
    const float* vw  = (const float*)d_in[6];
    const float* vb  = (const float*)d_in[7];
    const float* lnw = (const float*)d_in[8];
    const float* lnb = (const float*)d_in[9];

    const size_t tsz = (size_t)BATCH * NPOS * CDIM;
    f16* Qg  = (f16*)d_ws;
    f16* Kg  = Qg + tsz;
    f16* Vg  = Kg + tsz;
    float* out = (float*)d_out;

    void* args[] = {
        (void*)&x1, (void*)&x2, (void*)&qw, (void*)&kw, (void*)&vw,
        (void*)&qb, (void*)&kb, (void*)&vb, (void*)&lnw, (void*)&lnb,
        (void*)&Qg, (void*)&Kg, (void*)&Vg, (void*)&out
    };
    hipLaunchCooperativeKernel((void*)fused_kernel, dim3(256), dim3(512),
                               args, 0, stream);
}